// Round 6
// baseline (433.018 us; speedup 1.0000x reference)
//
#include <hip/hip_runtime.h>
#include <math.h>

// Problem constants
#define Bn    32
#define Tn    2000
#define Mrows (Bn * Tn)        // 64000
#define ENC2n 1024
#define ATTNn 512
#define DECn  512
#define NKn   10
#define KWn   100
#define PADn  50

// workspace layout (floats):
//   [0, 640000)            tmpconv [64000][10]
//   [OFF_DB, +16384)       DB[32][512] = b_enc + dec_e
//   [OFF_SCORE, +64000)    score [64000]
//   [OFF_WT, +262144)      Wt as f16 [512][1024]  (transposed W_enc)
#define OFF_DB    (Mrows * NKn)
#define OFF_SCORE (OFF_DB + Bn * ATTNn)
#define OFF_WT    (OFF_SCORE + Mrows)

typedef _Float16 v8h __attribute__((ext_vector_type(8)));
typedef float f32x4 __attribute__((ext_vector_type(4)));

__device__ __forceinline__ float fast_tanh(float v) {
  const float e = __expf(2.f * v);
  return 1.f - 2.f * __builtin_amdgcn_rcpf(e + 1.f);
}

// ---------------------------------------------------------------------------
// k_wt: W_enc [1024][512] f32 -> Wt [512][1024] f16 (transpose + convert, RNE)
// ---------------------------------------------------------------------------
__global__ __launch_bounds__(256) void k_wt(const float* __restrict__ W,
                                            _Float16* __restrict__ Wt) {
  __shared__ float sh[32][33];
  const int x = threadIdx.x & 31, y = threadIdx.x >> 5;  // y: 0..7
  const int k0 = blockIdx.x * 32, c0 = blockIdx.y * 32;
  for (int i = y; i < 32; i += 8) sh[i][x] = W[(size_t)(k0 + i) * ATTNn + c0 + x];
  __syncthreads();
  for (int i = y; i < 32; i += 8)
    Wt[(size_t)(c0 + i) * ENC2n + k0 + x] = (_Float16)sh[x][i];
}

// ---------------------------------------------------------------------------
// k_conv: tmpconv[b,t,k] = sum_i alpha[b,t+i-50]*Wconv[k,i]; zero score acc
// ---------------------------------------------------------------------------
__global__ __launch_bounds__(256) void k_conv(const float* __restrict__ alpha,
                                              const float* __restrict__ Wconv,
                                              float* __restrict__ ws) {
  __shared__ float sh[256 + KWn - 1];
  __shared__ float wc[NKn * KWn];
  const int b = blockIdx.y;
  const int t0 = blockIdx.x * 256;
  const int tid = threadIdx.x;

  for (int i = tid; i < NKn * KWn; i += 256) wc[i] = Wconv[i];
  const float* __restrict__ arow = alpha + b * Tn;
  for (int i = tid; i < 256 + KWn - 1; i += 256) {
    const int t = t0 - PADn + i;
    sh[i] = (t >= 0 && t < Tn) ? arow[t] : 0.f;
  }
  __syncthreads();

  const int t = t0 + tid;
  if (t < Tn) {
    float acc[NKn];
#pragma unroll
    for (int k = 0; k < NKn; ++k) acc[k] = 0.f;
    for (int i = 0; i < KWn; ++i) {
      const float a = sh[tid + i];
#pragma unroll
      for (int k = 0; k < NKn; ++k) acc[k] = fmaf(a, wc[k * KWn + i], acc[k]);
    }
    float* tp = ws + (size_t)(b * Tn + t) * NKn;
#pragma unroll
    for (int k = 0; k < NKn; ++k) tp[k] = acc[k];
    ws[OFF_SCORE + b * Tn + t] = 0.f;
  }
}

// ---------------------------------------------------------------------------
// k_dec: DB[b,a] = b_enc[a] + sum_d h[b,d]*Wdec[d,a]
// ---------------------------------------------------------------------------
__global__ __launch_bounds__(512) void k_dec(const float* __restrict__ h,
                                             const float* __restrict__ Wdec,
                                             const float* __restrict__ benc,
                                             float* __restrict__ ws) {
  __shared__ float sh[DECn];
  const int b = blockIdx.x;
  const int a = threadIdx.x;
  sh[a] = h[b * DECn + a];
  __syncthreads();
  float acc = 0.f;
  for (int d = 0; d < DECn; ++d) acc = fmaf(sh[d], Wdec[d * ATTNn + a], acc);
  ws[OFF_DB + b * ATTNn + a] = benc[a] + acc;
}

// ---------------------------------------------------------------------------
// k_main: fused f16-MFMA GEMM + DB + conv-expansion + tanh + score.
// 128x128 tile, BK=32, 3-DEEP split pipeline: loads for tile t+3 issued at
// phase t; cvt+ds_write of tile t+1 consumes loads issued 2 phases earlier
// (compiler emits counted vmcnt ~12). Raw s_barrier + lgkmcnt(0) only (no
// vmcnt drain). FRAGMENT-MAJOR LDS layout [fr][lg][lr][8]: a wave's
// ds_read_b128 = base + lane*16 (sequential, zero bank conflicts); staging
// writes hit 64 distinct dense 16B slots. 32 KB LDS total.
// ---------------------------------------------------------------------------
#define BM 128
#define BN 128
#define BK 32
#define NT (ENC2n / BK)   // 32
#define FBUF 4096         // f16 per buffer: 8 fr * 4 lg * 16 lr * 8

#define LOADT(P, kn)                               \
  P##a0 = *(const float4*)(asrc + (kn));           \
  P##a1 = *(const float4*)(asrc + (kn) + 4);       \
  P##a2 = *(const float4*)(asrc + (kn) + 8);       \
  P##a3 = *(const float4*)(asrc + (kn) + 12);      \
  P##w0 = *(const v8h*)(wsrc + (kn));              \
  P##w1 = *(const v8h*)(wsrc + (kn) + 8);

#define STORET(buf, P) {                                                     \
  v8h h0, h1;                                                                \
  h0[0]=(_Float16)P##a0.x; h0[1]=(_Float16)P##a0.y; h0[2]=(_Float16)P##a0.z; \
  h0[3]=(_Float16)P##a0.w; h0[4]=(_Float16)P##a1.x; h0[5]=(_Float16)P##a1.y; \
  h0[6]=(_Float16)P##a1.z; h0[7]=(_Float16)P##a1.w;                          \
  h1[0]=(_Float16)P##a2.x; h1[1]=(_Float16)P##a2.y; h1[2]=(_Float16)P##a2.z; \
  h1[3]=(_Float16)P##a2.w; h1[4]=(_Float16)P##a3.x; h1[5]=(_Float16)P##a3.y; \
  h1[6]=(_Float16)P##a3.z; h1[7]=(_Float16)P##a3.w;                          \
  *(v8h*)&AslF[(buf) * FBUF + soff]       = h0;                              \
  *(v8h*)&AslF[(buf) * FBUF + soff + 128] = h1;                              \
  *(v8h*)&WslF[(buf) * FBUF + soff]       = P##w0;                           \
  *(v8h*)&WslF[(buf) * FBUF + soff + 128] = P##w1; }

#define COMPUTET(buf) {                                                      \
  v8h af[4], bf[4];                                                          \
  _Pragma("unroll")                                                          \
  for (int m = 0; m < 4; ++m)                                                \
    af[m] = *(const v8h*)&AslF[(buf) * FBUF + (wm * 4 + m) * 512 + ra];      \
  _Pragma("unroll")                                                          \
  for (int n = 0; n < 4; ++n)                                                \
    bf[n] = *(const v8h*)&WslF[(buf) * FBUF + (wn * 4 + n) * 512 + ra];      \
  __builtin_amdgcn_s_setprio(1);                                             \
  _Pragma("unroll")                                                          \
  for (int m = 0; m < 4; ++m)                                                \
    _Pragma("unroll")                                                        \
    for (int n = 0; n < 4; ++n)                                              \
      acc[m][n] = __builtin_amdgcn_mfma_f32_16x16x32_f16(af[m], bf[n],       \
                                                         acc[m][n], 0, 0, 0);\
  __builtin_amdgcn_s_setprio(0); }

#define BARRIER() {                                                          \
  asm volatile("s_waitcnt lgkmcnt(0)" ::: "memory");                         \
  __builtin_amdgcn_s_barrier(); }

#define PHASE_LCS(Bl, cb, Bs, sb, kn) \
  LOADT(Bl, kn); COMPUTET(cb); STORET(sb, Bs); BARRIER();
#define PHASE_CS(cb, Bs, sb) \
  COMPUTET(cb); STORET(sb, Bs); BARRIER();

__global__ __launch_bounds__(256, 3) void k_main(
    const float* __restrict__ A,        // [64000][1024] f32
    const _Float16* __restrict__ Wt,    // [512][1024] f16
    const float* __restrict__ Wc2s,     // [10][512]
    const float* __restrict__ wscore,   // [512]
    float* __restrict__ ws) {
  __shared__ _Float16 AslF[2 * FBUF];   // 16 KB
  __shared__ _Float16 WslF[2 * FBUF];   // 16 KB
  const int tid = threadIdx.x;
  const int lane = tid & 63;
  const int wv = tid >> 6;
  const int wm = wv >> 1, wn = wv & 1;

  // XCD-chunked bijective swizzle (2000 = 8*250); 4 col-blocks of a row
  // panel adjacent within a chunk -> A panel fetched ~once per XCD/L2.
  const int l = blockIdx.x;
  const int lp = (l & 7) * 250 + (l >> 3);
  const int row0 = (lp >> 2) * BM;
  const int c0 = (lp & 3) * BN;

  // staging map: thread -> row sr = tid>>1, f16 k-offset (tid&1)*16
  const int sr = tid >> 1;
  const int sk = (tid & 1) * 16;                 // f32/f16 k offset
  // fragment-major LDS slot for this thread's h0 write:
  //   fr = sr>>4, lg = (tid&1)*2, lr = sr&15 -> ((fr*4+lg)*16+lr)*8
  const int soff = (((sr >> 4) * 4 + (tid & 1) * 2) * 16 + (sr & 15)) * 8;
  const float* __restrict__ asrc = A + (size_t)(row0 + sr) * ENC2n + sk;
  const _Float16* __restrict__ wsrc = Wt + (size_t)(c0 + sr) * ENC2n + sk;

  const int ra = lane * 8;                       // frag read: base + lane*16B

  f32x4 acc[4][4];
#pragma unroll
  for (int m = 0; m < 4; ++m)
#pragma unroll
    for (int n = 0; n < 4; ++n) acc[m][n] = (f32x4)0.f;

  // three register batches
  float4 Xa0, Xa1, Xa2, Xa3; v8h Xw0, Xw1;
  float4 Ya0, Ya1, Ya2, Ya3; v8h Yw0, Yw1;
  float4 Za0, Za1, Za2, Za3; v8h Zw0, Zw1;

  // ---- prologue: tiles 0,1,2 in flight; tile 0 -> buf 0 ----
  LOADT(X, 0);
  LOADT(Y, BK);
  LOADT(Z, 2 * BK);
  STORET(0, X);
  BARRIER();

  // ---- main: phase p computes tile p (buf p&1), stores tile p+1, loads p+3.
  // batch(t) = t%3; 6 phases per iteration (lcm of 2 bufs, 3 batches).
  for (int it = 0; it < 4; ++it) {
    const int b6 = it * 6;
    PHASE_LCS(X, 0, Y, 1, (b6 + 3) * BK);   // p=b6+0
    PHASE_LCS(Y, 1, Z, 0, (b6 + 4) * BK);   // p=b6+1
    PHASE_LCS(Z, 0, X, 1, (b6 + 5) * BK);   // p=b6+2
    PHASE_LCS(X, 1, Y, 0, (b6 + 6) * BK);   // p=b6+3
    PHASE_LCS(Y, 0, Z, 1, (b6 + 7) * BK);   // p=b6+4
    PHASE_LCS(Z, 1, X, 0, (b6 + 8) * BK);   // p=b6+5
  }
  // tail: p = 24..31
  PHASE_LCS(X, 0, Y, 1, 27 * BK);   // p24
  PHASE_LCS(Y, 1, Z, 0, 28 * BK);   // p25
  PHASE_LCS(Z, 0, X, 1, 29 * BK);   // p26
  PHASE_LCS(X, 1, Y, 0, 30 * BK);   // p27
  PHASE_LCS(Y, 0, Z, 1, 31 * BK);   // p28
  PHASE_CS(1, X, 0);                // p29: compute 29, store tile 30
  PHASE_CS(0, Y, 1);                // p30: compute 30, store tile 31
  COMPUTET(1);                      // p31

  // ---- epilogue ----
  __syncthreads();
  float* tcs = (float*)&AslF[0];          // reuse LDS: tmpconv slice [128][10]
  {
    const float* __restrict__ tsrc = ws + (size_t)row0 * NKn;
    for (int i = tid; i < BM * NKn; i += 256) tcs[i] = tsrc[i];
  }
  __syncthreads();

  const float* __restrict__ DB = ws + OFF_DB;
  const int lr = lane & 15, lg = lane >> 4;
  float wc2[4][NKn], wsc[4];
  int cl[4];
#pragma unroll
  for (int fn = 0; fn < 4; ++fn) {
    cl[fn] = c0 + wn * 64 + fn * 16 + lr;
    wsc[fn] = wscore[cl[fn]];
#pragma unroll
    for (int k = 0; k < NKn; ++k) wc2[fn][k] = Wc2s[k * ATTNn + cl[fn]];
  }

#pragma unroll
  for (int fm = 0; fm < 4; ++fm) {
#pragma unroll
    for (int r = 0; r < 4; ++r) {
      const int rowL = wm * 64 + fm * 16 + lg * 4 + r;
      const int grow = row0 + rowL;
      const int b = grow / Tn;
      const float* __restrict__ tk = &tcs[rowL * NKn];
      float tkv[NKn];
#pragma unroll
      for (int k = 0; k < NKn; ++k) tkv[k] = tk[k];
      float p = 0.f;
#pragma unroll
      for (int fn = 0; fn < 4; ++fn) {
        float v = acc[fm][fn][r] + DB[b * ATTNn + cl[fn]];
#pragma unroll
        for (int k = 0; k < NKn; ++k) v = fmaf(tkv[k], wc2[fn][k], v);
        p = fmaf(wsc[fn], fast_tanh(v), p);
      }
      p += __shfl_down(p, 8, 16);
      p += __shfl_down(p, 4, 16);
      p += __shfl_down(p, 2, 16);
      p += __shfl_down(p, 1, 16);
      if (lr == 0) atomicAdd(&ws[OFF_SCORE + grow], p);
    }
  }
}

// ---------------------------------------------------------------------------
// k_softmax: masked softmax over T per batch row
// ---------------------------------------------------------------------------
__global__ __launch_bounds__(256) void k_softmax(const float* __restrict__ ws,
                                                 const float* __restrict__ mask,
                                                 float* __restrict__ out) {
  const int b = blockIdx.x, tid = threadIdx.x;
  const float* __restrict__ s = ws + OFF_SCORE + b * Tn;
  const float* __restrict__ mrow = mask + b * Tn;
  float* __restrict__ orow = out + b * Tn;
  __shared__ float red[4];

  float m = -1e30f;
  for (int t = tid; t < Tn; t += 256) m = fmaxf(m, s[t]);
#pragma unroll
  for (int off = 32; off; off >>= 1) m = fmaxf(m, __shfl_down(m, off));
  if ((tid & 63) == 0) red[tid >> 6] = m;
  __syncthreads();
  m = fmaxf(fmaxf(red[0], red[1]), fmaxf(red[2], red[3]));
  __syncthreads();

  float sum = 0.f;
  for (int t = tid; t < Tn; t += 256) {
    const float e = expf(s[t] - m) * mrow[t];
    orow[t] = e;
    sum += e;
  }
#pragma unroll
  for (int off = 32; off; off >>= 1) sum += __shfl_down(sum, off);
  if ((tid & 63) == 0) red[tid >> 6] = sum;
  __syncthreads();
  sum = red[0] + red[1] + red[2] + red[3];
  const float inv = 1.f / sum;
  for (int t = tid; t < Tn; t += 256) orow[t] *= inv;
}

// ---------------------------------------------------------------------------
extern "C" void kernel_launch(void* const* d_in, const int* in_sizes, int n_in,
                              void* d_out, int out_size, void* d_ws, size_t ws_size,
                              hipStream_t stream) {
  const float* enc   = (const float*)d_in[0];
  const float* hid   = (const float*)d_in[1];
  const float* alpha = (const float*)d_in[2];
  const float* mask  = (const float*)d_in[3];
  const float* Wconv = (const float*)d_in[4];
  const float* Wc2s  = (const float*)d_in[5];
  const float* Wenc  = (const float*)d_in[6];
  const float* benc  = (const float*)d_in[7];
  const float* Wdec  = (const float*)d_in[8];
  const float* wscr  = (const float*)d_in[9];
  float* out = (float*)d_out;
  float* ws  = (float*)d_ws;
  _Float16* Wt = (_Float16*)(ws + OFF_WT);

  k_wt<<<dim3(ENC2n / 32, ATTNn / 32), 256, 0, stream>>>(Wenc, Wt);
  k_conv<<<dim3((Tn + 255) / 256, Bn), 256, 0, stream>>>(alpha, Wconv, ws);
  k_dec<<<Bn, DECn, 0, stream>>>(hid, Wdec, benc, ws);
  k_main<<<2000, 256, 0, stream>>>(enc, Wt, Wc2s, wscr, ws);
  k_softmax<<<Bn, 256, 0, stream>>>(ws, mask, out);
}

// Round 8
// 323.469 us; speedup vs baseline: 1.3387x; 1.3387x over previous
//
#include <hip/hip_runtime.h>
#include <math.h>

// Problem constants
#define Bn    32
#define Tn    2000
#define Mrows (Bn * Tn)        // 64000
#define ENC2n 1024
#define ATTNn 512
#define DECn  512
#define NKn   10
#define KWn   100
#define PADn  50

// workspace layout (floats):
//   [0, 640000)            tmpconv [64000][10]
//   [OFF_DB, +16384)       DB[32][512] = b_enc + dec_e
//   [OFF_SCORE, +64000)    score [64000]
//   [OFF_WT, +262144)      Wswz f16 [4 cb][32 kt][4096]  (DMA-order W_enc)
#define OFF_DB    (Mrows * NKn)
#define OFF_SCORE (OFF_DB + Bn * ATTNn)
#define OFF_WT    (OFF_SCORE + Mrows)

typedef _Float16 v8h __attribute__((ext_vector_type(8)));
typedef float f32x4 __attribute__((ext_vector_type(4)));

__device__ __forceinline__ float fast_tanh(float v) {
  const float e = __expf(2.f * v);
  return 1.f - 2.f * __builtin_amdgcn_rcpf(e + 1.f);
}

__device__ __forceinline__ void gload_lds16(const void* g, void* l) {
  __builtin_amdgcn_global_load_lds(
      (const __attribute__((address_space(1))) void*)g,
      (__attribute__((address_space(3))) void*)l, 16, 0, 0);
}

// ---------------------------------------------------------------------------
// k_wswz: W_enc [1024k][512c] f32 -> Wswz f16 in DMA-consumption order:
//   within (cb,kt) block of 4096: j = fn*512 + lg*128 + lr*8 + e holds
//   W[(kt*32 + lg*8 + e)*512 + cb*128 + fn*16 + lr]
// ---------------------------------------------------------------------------
__global__ __launch_bounds__(256) void k_wswz(const float* __restrict__ W,
                                              _Float16* __restrict__ Wz) {
  const int idx = blockIdx.x * 256 + threadIdx.x;   // 65536 slots of 8
  const int cb = idx >> 14;
  const int kt = (idx >> 9) & 31;
  const int s = idx & 511;
  const int fn = s >> 6, lg = (s >> 4) & 3, lr = s & 15;
  const int col = cb * 128 + fn * 16 + lr;
  const int k0 = kt * 32 + lg * 8;
  v8h h;
#pragma unroll
  for (int e = 0; e < 8; ++e) h[e] = (_Float16)W[(size_t)(k0 + e) * ATTNn + col];
  *(v8h*)&Wz[(size_t)idx * 8] = h;
}

// ---------------------------------------------------------------------------
// k_conv: tmpconv[b,t,k] = sum_i alpha[b,t+i-50]*Wconv[k,i]; zero score acc
// ---------------------------------------------------------------------------
__global__ __launch_bounds__(256) void k_conv(const float* __restrict__ alpha,
                                              const float* __restrict__ Wconv,
                                              float* __restrict__ ws) {
  __shared__ float sh[256 + KWn - 1];
  __shared__ float wc[NKn * KWn];
  const int b = blockIdx.y;
  const int t0 = blockIdx.x * 256;
  const int tid = threadIdx.x;

  for (int i = tid; i < NKn * KWn; i += 256) wc[i] = Wconv[i];
  const float* __restrict__ arow = alpha + b * Tn;
  for (int i = tid; i < 256 + KWn - 1; i += 256) {
    const int t = t0 - PADn + i;
    sh[i] = (t >= 0 && t < Tn) ? arow[t] : 0.f;
  }
  __syncthreads();

  const int t = t0 + tid;
  if (t < Tn) {
    float acc[NKn];
#pragma unroll
    for (int k = 0; k < NKn; ++k) acc[k] = 0.f;
    for (int i = 0; i < KWn; ++i) {
      const float a = sh[tid + i];
#pragma unroll
      for (int k = 0; k < NKn; ++k) acc[k] = fmaf(a, wc[k * KWn + i], acc[k]);
    }
    float* tp = ws + (size_t)(b * Tn + t) * NKn;
#pragma unroll
    for (int k = 0; k < NKn; ++k) tp[k] = acc[k];
    ws[OFF_SCORE + b * Tn + t] = 0.f;
  }
}

// ---------------------------------------------------------------------------
// k_dec: DB[b,a] = b_enc[a] + sum_d h[b,d]*Wdec[d,a]
// ---------------------------------------------------------------------------
__global__ __launch_bounds__(512) void k_dec(const float* __restrict__ h,
                                             const float* __restrict__ Wdec,
                                             const float* __restrict__ benc,
                                             float* __restrict__ ws) {
  __shared__ float sh[DECn];
  const int b = blockIdx.x;
  const int a = threadIdx.x;
  sh[a] = h[b * DECn + a];
  __syncthreads();
  float acc = 0.f;
  for (int d = 0; d < DECn; ++d) acc = fmaf(sh[d], Wdec[d * ATTNn + a], acc);
  ws[OFF_DB + b * ATTNn + a] = benc[a] + acc;
}

// ---------------------------------------------------------------------------
// k_main: fused f16-MFMA GEMM + DB + conv-expansion + tanh + score.
// 128x128, BK=32, 32 phases. A: reg-staged depth-3 (3 batches x 16 VGPR,
// A-only), cvt f32->f16, ds_write into fragment-major Ab[2] (wave-contiguous
// writes, zero conflicts). W: global_load_lds DMA from pre-swizzled Wswz into
// Wb[3] (contiguous 1KB per wave-round, linear dest, zero VGPR). Steady
// barrier = s_waitcnt vmcnt(6) lgkmcnt(0) + raw s_barrier: forces exactly the
// PREVIOUS phase's A-batch + W-DMA, leaves current phase's 6 in flight ->
// ~1.5-phase latency cover. All MFMA-operand reads are base + lane*16B.
// ---------------------------------------------------------------------------
#define BM 128
#define BN 128
#define BK 32
#define NT (ENC2n / BK)   // 32

#define LOADA(P, kn)                            \
  P##0 = *(const float4*)(asrc + (kn));         \
  P##1 = *(const float4*)(asrc + (kn) + 4);     \
  P##2 = *(const float4*)(asrc2 + (kn));        \
  P##3 = *(const float4*)(asrc2 + (kn) + 4);

#define CVTSTORE(P, ab) {                                                    \
  v8h h0, h1;                                                                \
  h0[0] = (_Float16)(P##0).x; h0[1] = (_Float16)(P##0).y;                    \
  h0[2] = (_Float16)(P##0).z; h0[3] = (_Float16)(P##0).w;                    \
  h0[4] = (_Float16)(P##1).x; h0[5] = (_Float16)(P##1).y;                    \
  h0[6] = (_Float16)(P##1).z; h0[7] = (_Float16)(P##1).w;                    \
  h1[0] = (_Float16)(P##2).x; h1[1] = (_Float16)(P##2).y;                    \
  h1[2] = (_Float16)(P##2).z; h1[3] = (_Float16)(P##2).w;                    \
  h1[4] = (_Float16)(P##3).x; h1[5] = (_Float16)(P##3).y;                    \
  h1[6] = (_Float16)(P##3).z; h1[7] = (_Float16)(P##3).w;                    \
  *(v8h*)&Ab[ab][tid * 8]        = h0;                                       \
  *(v8h*)&Ab[ab][tid * 8 + 2048] = h1; }

#define WDMA(wb, kt) {                                                       \
  const _Float16* g0 = wswz + (((size_t)(kt)) << 12) + (wv * 2) * 512 + lane * 8; \
  gload_lds16(g0,        &Wb[wb][(wv * 2) * 512]);                           \
  gload_lds16(g0 + 512,  &Wb[wb][(wv * 2 + 1) * 512]); }

#define COMPUTE(ab, wb) {                                                    \
  v8h af[4], bf[4];                                                          \
  _Pragma("unroll")                                                          \
  for (int m = 0; m < 4; ++m)                                                \
    af[m] = *(const v8h*)&Ab[ab][((wm * 4 + m) * 64 + lane) * 8];            \
  _Pragma("unroll")                                                          \
  for (int n = 0; n < 4; ++n)                                                \
    bf[n] = *(const v8h*)&Wb[wb][((wn * 4 + n) * 64 + lane) * 8];            \
  __builtin_amdgcn_s_setprio(1);                                             \
  _Pragma("unroll")                                                          \
  for (int m = 0; m < 4; ++m)                                                \
    _Pragma("unroll")                                                        \
    for (int n = 0; n < 4; ++n)                                              \
      acc[m][n] = __builtin_amdgcn_mfma_f32_16x16x32_f16(af[m], bf[n],       \
                                                         acc[m][n], 0, 0, 0);\
  __builtin_amdgcn_s_setprio(0); }

#define BARN(N) {                                                            \
  asm volatile("s_waitcnt vmcnt(" #N ") lgkmcnt(0)" ::: "memory");           \
  __builtin_amdgcn_s_barrier(); }

// steady phase p: load A(p+3) -> batch p%3; DMA W(p+2) -> Wb[(p+2)%3];
// compute tile p from Ab[p&1], Wb[p%3]; cvt batch (p+1)%3 -> Ab[(p+1)&1].
#define PHASE(PN, ab, wb, wdst, Pl, Pc, kn) \
  LOADA(Pl, kn); WDMA(wdst, (kn) / BK - 1); COMPUTE(ab, wb); \
  CVTSTORE(Pc, ab ^ 1); BARN(6)

__global__ __launch_bounds__(256, 3) void k_main(
    const float* __restrict__ A,        // [64000][1024] f32
    const _Float16* __restrict__ Wz,    // swizzled W, f16
    const float* __restrict__ Wc2s,     // [10][512]
    const float* __restrict__ wscore,   // [512]
    float* __restrict__ ws) {
  __shared__ _Float16 Ab[2][4096];   // 16 KB
  __shared__ _Float16 Wb[3][4096];   // 24 KB
  const int tid = threadIdx.x;
  const int lane = tid & 63;
  const int wv = tid >> 6;
  const int wm = wv >> 1, wn = wv & 1;

  // XCD-chunked bijective swizzle (2000 = 8*250); 4 col-blocks adjacent.
  const int l = blockIdx.x;
  const int lp = (l & 7) * 250 + (l >> 3);
  const int row0 = (lp >> 2) * BM;
  const int cb = lp & 3;

  // A staging map: thread -> slots tid (h0, rows 0..63) and tid+256 (h1):
  //   row = (tid>>6)*16 + (tid&15), koff = ((tid>>4)&3)*8
  const int arow = (tid >> 6) * 16 + (tid & 15);
  const int akoff = ((tid >> 4) & 3) * 8;
  const float* __restrict__ asrc = A + (size_t)(row0 + arow) * ENC2n + akoff;
  const float* __restrict__ asrc2 = asrc + (size_t)64 * ENC2n;
  const _Float16* __restrict__ wswz = Wz + ((size_t)cb << 17);

  f32x4 acc[4][4];
#pragma unroll
  for (int m = 0; m < 4; ++m)
#pragma unroll
    for (int n = 0; n < 4; ++n) acc[m][n] = (f32x4)0.f;

  float4 X0, X1, X2, X3, Y0, Y1, Y2, Y3, Z0, Z1, Z2, Z3;

  // ---- prologue: A0,W0,W1,A1,A2 in flight; A0 -> Ab0 ----
  LOADA(X, 0);
  WDMA(0, 0);
  WDMA(1, 1);
  LOADA(Y, BK);
  LOADA(Z, 2 * BK);
  CVTSTORE(X, 0);
  BARN(10);   // forces A0, W0; leaves W1 + A1 + A2

  // ---- main loop: period 6 (Ab period 2 x batch/Wb period 3) ----
  for (int it = 0; it < 4; ++it) {
    const int p = it * 6;
    PHASE(p + 0, 0, 0, 2, X, Y, (p + 3) * BK);
    PHASE(p + 1, 1, 1, 0, Y, Z, (p + 4) * BK);
    PHASE(p + 2, 0, 2, 1, Z, X, (p + 5) * BK);
    PHASE(p + 3, 1, 0, 2, X, Y, (p + 6) * BK);
    PHASE(p + 4, 0, 1, 0, Y, Z, (p + 7) * BK);
    PHASE(p + 5, 1, 2, 1, Z, X, (p + 8) * BK);
  }
  // tail p = 24..31
  PHASE(24, 0, 0, 2, X, Y, 27 * BK);
  PHASE(25, 1, 1, 0, Y, Z, 28 * BK);
  PHASE(26, 0, 2, 1, Z, X, 29 * BK);
  PHASE(27, 1, 0, 2, X, Y, 30 * BK);
  PHASE(28, 0, 1, 0, Y, Z, 31 * BK);
  // p=29: no A-load; DMA W31 -> Wb1; compute 29 (Ab1,Wb2); cvt X(A30)->Ab0
  WDMA(1, 31);
  COMPUTE(1, 2);
  CVTSTORE(X, 0);
  BARN(0);
  // p=30: compute 30 (Ab0,Wb0); cvt Y(A31)->Ab1
  COMPUTE(0, 0);
  CVTSTORE(Y, 1);
  BARN(0);
  // p=31
  COMPUTE(1, 1);

  // ---- epilogue ----
  __syncthreads();
  float* tcs = (float*)&Ab[0][0];        // reuse LDS: tmpconv slice [128][10]
  {
    const float* __restrict__ tsrc = ws + (size_t)row0 * NKn;
    for (int i = tid; i < BM * NKn; i += 256) tcs[i] = tsrc[i];
  }
  __syncthreads();

  const int c0 = cb * BN;
  const float* __restrict__ DB = ws + OFF_DB;
  const int lr = lane & 15, lg = lane >> 4;
  float wc2[4][NKn], wsc[4];
  int cl[4];
#pragma unroll
  for (int fn = 0; fn < 4; ++fn) {
    cl[fn] = c0 + wn * 64 + fn * 16 + lr;
    wsc[fn] = wscore[cl[fn]];
#pragma unroll
    for (int k = 0; k < NKn; ++k) wc2[fn][k] = Wc2s[k * ATTNn + cl[fn]];
  }

#pragma unroll
  for (int fm = 0; fm < 4; ++fm) {
#pragma unroll
    for (int r = 0; r < 4; ++r) {
      const int rowL = wm * 64 + fm * 16 + lg * 4 + r;
      const int grow = row0 + rowL;
      const int b = grow / Tn;
      const float* __restrict__ tk = &tcs[rowL * NKn];
      float tkv[NKn];
#pragma unroll
      for (int k = 0; k < NKn; ++k) tkv[k] = tk[k];
      float p = 0.f;
#pragma unroll
      for (int fn = 0; fn < 4; ++fn) {
        float v = acc[fm][fn][r] + DB[b * ATTNn + cl[fn]];
#pragma unroll
        for (int k = 0; k < NKn; ++k) v = fmaf(tkv[k], wc2[fn][k], v);
        p = fmaf(wsc[fn], fast_tanh(v), p);
      }
      p += __shfl_down(p, 8, 16);
      p += __shfl_down(p, 4, 16);
      p += __shfl_down(p, 2, 16);
      p += __shfl_down(p, 1, 16);
      if (lr == 0) atomicAdd(&ws[OFF_SCORE + grow], p);
    }
  }
}

// ---------------------------------------------------------------------------
// k_softmax: masked softmax over T per batch row
// ---------------------------------------------------------------------------
__global__ __launch_bounds__(256) void k_softmax(const float* __restrict__ ws,
                                                 const float* __restrict__ mask,
                                                 float* __restrict__ out) {
  const int b = blockIdx.x, tid = threadIdx.x;
  const float* __restrict__ s = ws + OFF_SCORE + b * Tn;
  const float* __restrict__ mrow = mask + b * Tn;
  float* __restrict__ orow = out + b * Tn;
  __shared__ float red[4];

  float m = -1e30f;
  for (int t = tid; t < Tn; t += 256) m = fmaxf(m, s[t]);
#pragma unroll
  for (int off = 32; off; off >>= 1) m = fmaxf(m, __shfl_down(m, off));
  if ((tid & 63) == 0) red[tid >> 6] = m;
  __syncthreads();
  m = fmaxf(fmaxf(red[0], red[1]), fmaxf(red[2], red[3]));
  __syncthreads();

  float sum = 0.f;
  for (int t = tid; t < Tn; t += 256) {
    const float e = expf(s[t] - m) * mrow[t];
    orow[t] = e;
    sum += e;
  }
#pragma unroll
  for (int off = 32; off; off >>= 1) sum += __shfl_down(sum, off);
  if ((tid & 63) == 0) red[tid >> 6] = sum;
  __syncthreads();
  sum = red[0] + red[1] + red[2] + red[3];
  const float inv = 1.f / sum;
  for (int t = tid; t < Tn; t += 256) orow[t] *= inv;
}

// ---------------------------------------------------------------------------
extern "C" void kernel_launch(void* const* d_in, const int* in_sizes, int n_in,
                              void* d_out, int out_size, void* d_ws, size_t ws_size,
                              hipStream_t stream) {
  const float* enc   = (const float*)d_in[0];
  const float* hid   = (const float*)d_in[1];
  const float* alpha = (const float*)d_in[2];
  const float* mask  = (const float*)d_in[3];
  const float* Wconv = (const float*)d_in[4];
  const float* Wc2s  = (const float*)d_in[5];
  const float* Wenc  = (const float*)d_in[6];
  const float* benc  = (const float*)d_in[7];
  const float* Wdec  = (const float*)d_in[8];
  const float* wscr  = (const float*)d_in[9];
  float* out = (float*)d_out;
  float* ws  = (float*)d_ws;
  _Float16* Wz = (_Float16*)(ws + OFF_WT);

  k_wswz<<<256, 256, 0, stream>>>(Wenc, Wz);
  k_conv<<<dim3((Tn + 255) / 256, Bn), 256, 0, stream>>>(alpha, Wconv, ws);
  k_dec<<<Bn, DECn, 0, stream>>>(hid, Wdec, benc, ws);
  k_main<<<2000, 256, 0, stream>>>(enc, Wz, Wc2s, wscr, ws);
  k_softmax<<<Bn, 256, 0, stream>>>(ws, mask, out);
}

// Round 9
// 305.870 us; speedup vs baseline: 1.4157x; 1.0575x over previous
//
#include <hip/hip_runtime.h>
#include <math.h>

// Problem constants
#define Bn    32
#define Tn    2000
#define Mrows (Bn * Tn)        // 64000
#define ENC2n 1024
#define ATTNn 512
#define DECn  512
#define NKn   10
#define KWn   100
#define PADn  50

// workspace layout (floats):
//   [0, 640000)            tmpconv [64000][10]
//   [OFF_DB, +16384)       DB[32][512] = b_enc + dec_e
//   [OFF_SCORE, +64000)    score [64000]
//   [OFF_WT, +262144)      Wt f16 [512 col][1024 k]  (transposed W_enc)
//   [OFF_AF16, +32768000)  Af16 [64000][1024]  (f16 copy of enc_output)
#define OFF_DB    (Mrows * NKn)
#define OFF_SCORE (OFF_DB + Bn * ATTNn)
#define OFF_WT    (OFF_SCORE + Mrows)
#define OFF_AF16  (OFF_WT + 262144)
#define WS_NEED_BYTES ((size_t)OFF_AF16 * 4 + (size_t)Mrows * ENC2n * 2)

typedef _Float16 v8h __attribute__((ext_vector_type(8)));
typedef float f32x4 __attribute__((ext_vector_type(4)));

__device__ __forceinline__ float fast_tanh(float v) {
  const float e = __expf(2.f * v);
  return 1.f - 2.f * __builtin_amdgcn_rcpf(e + 1.f);
}

__device__ __forceinline__ void gload_lds16(const void* g, void* l) {
  __builtin_amdgcn_global_load_lds(
      (const __attribute__((address_space(1))) void*)g,
      (__attribute__((address_space(3))) void*)l, 16, 0, 0);
}

// ---------------------------------------------------------------------------
// k_wt: W_enc [1024][512] f32 -> Wt [512][1024] f16 (transpose + convert, RNE)
// ---------------------------------------------------------------------------
__global__ __launch_bounds__(256) void k_wt(const float* __restrict__ W,
                                            _Float16* __restrict__ Wt) {
  __shared__ float sh[32][33];
  const int x = threadIdx.x & 31, y = threadIdx.x >> 5;  // y: 0..7
  const int k0 = blockIdx.x * 32, c0 = blockIdx.y * 32;
  for (int i = y; i < 32; i += 8) sh[i][x] = W[(size_t)(k0 + i) * ATTNn + c0 + x];
  __syncthreads();
  for (int i = y; i < 32; i += 8)
    Wt[(size_t)(c0 + i) * ENC2n + k0 + x] = (_Float16)sh[x][i];
}

// ---------------------------------------------------------------------------
// k_acvt: Af16 = (f16)enc_output, pure streaming (grid-stride)
// ---------------------------------------------------------------------------
__global__ __launch_bounds__(256) void k_acvt(const float* __restrict__ A,
                                              _Float16* __restrict__ Af) {
  const size_t total = (size_t)Mrows * ENC2n;
  const size_t stride = (size_t)gridDim.x * 256 * 8;
  for (size_t i = ((size_t)blockIdx.x * 256 + threadIdx.x) * 8; i < total;
       i += stride) {
    const float4 a = *(const float4*)(A + i);
    const float4 b = *(const float4*)(A + i + 4);
    v8h h;
    h[0] = (_Float16)a.x; h[1] = (_Float16)a.y;
    h[2] = (_Float16)a.z; h[3] = (_Float16)a.w;
    h[4] = (_Float16)b.x; h[5] = (_Float16)b.y;
    h[6] = (_Float16)b.z; h[7] = (_Float16)b.w;
    *(v8h*)(Af + i) = h;
  }
}

// ---------------------------------------------------------------------------
// k_conv: tmpconv[b,t,k] = sum_i alpha[b,t+i-50]*Wconv[k,i]; zero score acc
// ---------------------------------------------------------------------------
__global__ __launch_bounds__(256) void k_conv(const float* __restrict__ alpha,
                                              const float* __restrict__ Wconv,
                                              float* __restrict__ ws) {
  __shared__ float sh[256 + KWn - 1];
  __shared__ float wc[NKn * KWn];
  const int b = blockIdx.y;
  const int t0 = blockIdx.x * 256;
  const int tid = threadIdx.x;

  for (int i = tid; i < NKn * KWn; i += 256) wc[i] = Wconv[i];
  const float* __restrict__ arow = alpha + b * Tn;
  for (int i = tid; i < 256 + KWn - 1; i += 256) {
    const int t = t0 - PADn + i;
    sh[i] = (t >= 0 && t < Tn) ? arow[t] : 0.f;
  }
  __syncthreads();

  const int t = t0 + tid;
  if (t < Tn) {
    float acc[NKn];
#pragma unroll
    for (int k = 0; k < NKn; ++k) acc[k] = 0.f;
    for (int i = 0; i < KWn; ++i) {
      const float a = sh[tid + i];
#pragma unroll
      for (int k = 0; k < NKn; ++k) acc[k] = fmaf(a, wc[k * KWn + i], acc[k]);
    }
    float* tp = ws + (size_t)(b * Tn + t) * NKn;
#pragma unroll
    for (int k = 0; k < NKn; ++k) tp[k] = acc[k];
    ws[OFF_SCORE + b * Tn + t] = 0.f;
  }
}

// ---------------------------------------------------------------------------
// k_dec: DB[b,a] = b_enc[a] + sum_d h[b,d]*Wdec[d,a]
// ---------------------------------------------------------------------------
__global__ __launch_bounds__(512) void k_dec(const float* __restrict__ h,
                                             const float* __restrict__ Wdec,
                                             const float* __restrict__ benc,
                                             float* __restrict__ ws) {
  __shared__ float sh[DECn];
  const int b = blockIdx.x;
  const int a = threadIdx.x;
  sh[a] = h[b * DECn + a];
  __syncthreads();
  float acc = 0.f;
  for (int d = 0; d < DECn; ++d) acc = fmaf(sh[d], Wdec[d * ATTNn + a], acc);
  ws[OFF_DB + b * ATTNn + a] = benc[a] + acc;
}

#define BM 128
#define BN 128
#define BK 32
#define NT (ENC2n / BK)   // 32

// ---------------------------------------------------------------------------
// k_main (DMA path): both operands via global_load_lds with PER-LANE global
// sources (row-major Af16/Wt) into fragment-major LDS (linear dest, lane*16B).
// Zero staging VGPRs, zero ds_writes, zero cvt in the loop. 4 buffers each,
// depth-3 issue-ahead, counted vmcnt(8) barrier (12 in flight, force oldest
// tile). kt offsets fold into the DMA immediate. Per phase/wave: 4 DMA issues
// + 8 ds_read_b128 + 16 MFMA.
// ---------------------------------------------------------------------------
#define DMAT(buf, kt) {                                                      \
  gload_lds16(aA0 + (kt) * BK, &Ab[buf][(2 * wv) * 512]);                    \
  gload_lds16(aA1 + (kt) * BK, &Ab[buf][(2 * wv + 1) * 512]);                \
  gload_lds16(aW0 + (kt) * BK, &Wb[buf][(2 * wv) * 512]);                    \
  gload_lds16(aW1 + (kt) * BK, &Wb[buf][(2 * wv + 1) * 512]); }

#define COMPUTE(buf) {                                                       \
  v8h af[4], bf[4];                                                          \
  _Pragma("unroll")                                                          \
  for (int m = 0; m < 4; ++m)                                                \
    af[m] = *(const v8h*)&Ab[buf][(wm * 4 + m) * 512 + lane * 8];            \
  _Pragma("unroll")                                                          \
  for (int n = 0; n < 4; ++n)                                                \
    bf[n] = *(const v8h*)&Wb[buf][(wn * 4 + n) * 512 + lane * 8];            \
  __builtin_amdgcn_s_setprio(1);                                             \
  _Pragma("unroll")                                                          \
  for (int m = 0; m < 4; ++m)                                                \
    _Pragma("unroll")                                                        \
    for (int n = 0; n < 4; ++n)                                              \
      acc[m][n] = __builtin_amdgcn_mfma_f32_16x16x32_f16(af[m], bf[n],       \
                                                         acc[m][n], 0, 0, 0);\
  __builtin_amdgcn_s_setprio(0); }

#define BARN(N) {                                                            \
  asm volatile("s_waitcnt vmcnt(" #N ") lgkmcnt(0)" ::: "memory");           \
  __builtin_amdgcn_s_barrier(); }

#define PHASE(cbuf, dbuf, ktd) DMAT(dbuf, ktd); COMPUTE(cbuf); BARN(8)

__global__ __launch_bounds__(256, 2) void k_main(
    const _Float16* __restrict__ Af,    // [64000][1024] f16
    const _Float16* __restrict__ Wt,    // [512][1024] f16
    const float* __restrict__ Wc2s,     // [10][512]
    const float* __restrict__ wscore,   // [512]
    float* __restrict__ ws) {
  __shared__ _Float16 Ab[4][4096];   // 32 KB
  __shared__ _Float16 Wb[4][4096];   // 32 KB
  const int tid = threadIdx.x;
  const int lane = tid & 63;
  const int wv = tid >> 6;
  const int wm = wv >> 1, wn = wv & 1;

  // XCD-chunked bijective swizzle (2000 = 8*250); 4 col-blocks adjacent.
  const int l = blockIdx.x;
  const int lp = (l & 7) * 250 + (l >> 3);
  const int row0 = (lp >> 2) * BM;
  const int c0 = (lp & 3) * BN;

  // per-lane DMA source bases: chunk c rows/cols c*16 + (lane&15),
  // k-slice (lane>>4)*8. Wave wv owns chunks 2wv, 2wv+1.
  const int lsub = (lane & 15), ksl = (lane >> 4) * 8;
  const _Float16* aA0 = Af + (size_t)(row0 + 2 * wv * 16 + lsub) * ENC2n + ksl;
  const _Float16* aA1 = aA0 + (size_t)16 * ENC2n;
  const _Float16* aW0 = Wt + (size_t)(c0 + 2 * wv * 16 + lsub) * ENC2n + ksl;
  const _Float16* aW1 = aW0 + (size_t)16 * ENC2n;

  f32x4 acc[4][4];
#pragma unroll
  for (int m = 0; m < 4; ++m)
#pragma unroll
    for (int n = 0; n < 4; ++n) acc[m][n] = (f32x4)0.f;

  // ---- prologue: tiles 0,1,2 in flight (12 per wave); force tile 0 ----
  DMAT(0, 0);
  DMAT(1, 1);
  DMAT(2, 2);
  BARN(8);

  // ---- 32 phases: compute p from buf p%4; DMA tile p+3 -> buf (p+3)%4 ----
  for (int it = 0; it < 7; ++it) {
    const int p = it * 4;
    PHASE(0, 3, p + 3);
    PHASE(1, 0, p + 4);
    PHASE(2, 1, p + 5);
    PHASE(3, 2, p + 6);
  }
  PHASE(0, 3, 31);        // p=28, DMA tile 31
  COMPUTE(1); BARN(4);    // p=29, force tile 30
  COMPUTE(2); BARN(0);    // p=30, force tile 31
  COMPUTE(3);             // p=31

  // ---- epilogue ----
  __syncthreads();
  float* tcs = (float*)&Ab[0][0];        // reuse LDS: tmpconv slice [128][10]
  {
    const float* __restrict__ tsrc = ws + (size_t)row0 * NKn;
    for (int i = tid; i < BM * NKn; i += 256) tcs[i] = tsrc[i];
  }
  __syncthreads();

  const float* __restrict__ DB = ws + OFF_DB;
  const int lr = lane & 15, lg = lane >> 4;
  float wc2[4][NKn], wsc[4];
  int cl[4];
#pragma unroll
  for (int fn = 0; fn < 4; ++fn) {
    cl[fn] = c0 + wn * 64 + fn * 16 + lr;
    wsc[fn] = wscore[cl[fn]];
#pragma unroll
    for (int k = 0; k < NKn; ++k) wc2[fn][k] = Wc2s[k * ATTNn + cl[fn]];
  }

#pragma unroll
  for (int fm = 0; fm < 4; ++fm) {
#pragma unroll
    for (int r = 0; r < 4; ++r) {
      const int rowL = wm * 64 + fm * 16 + lg * 4 + r;
      const int grow = row0 + rowL;
      const int b = grow / Tn;
      const float* __restrict__ tk = &tcs[rowL * NKn];
      float tkv[NKn];
#pragma unroll
      for (int k = 0; k < NKn; ++k) tkv[k] = tk[k];
      float p = 0.f;
#pragma unroll
      for (int fn = 0; fn < 4; ++fn) {
        float v = acc[fm][fn][r] + DB[b * ATTNn + cl[fn]];
#pragma unroll
        for (int k = 0; k < NKn; ++k) v = fmaf(tkv[k], wc2[fn][k], v);
        p = fmaf(wsc[fn], fast_tanh(v), p);
      }
      p += __shfl_down(p, 8, 16);
      p += __shfl_down(p, 4, 16);
      p += __shfl_down(p, 2, 16);
      p += __shfl_down(p, 1, 16);
      if (lr == 0) atomicAdd(&ws[OFF_SCORE + grow], p);
    }
  }
}

// ---------------------------------------------------------------------------
// k_main5: fallback (R5, proven 218 us) if ws_size can't hold Af16.
// ---------------------------------------------------------------------------
#define LDKh 40

#define LOADT5(Pa0, Pa1, Pa2, Pa3, Pw0, Pw1, kn)    \
  Pa0 = *(const float4*)(asrc + (kn));              \
  Pa1 = *(const float4*)(asrc + (kn) + 4);          \
  Pa2 = *(const float4*)(asrc + (kn) + 8);          \
  Pa3 = *(const float4*)(asrc + (kn) + 12);         \
  Pw0 = *(const v8h*)(wsrc + (kn));                 \
  Pw1 = *(const v8h*)(wsrc + (kn) + 8);

#define STORET5(buf, Pa0, Pa1, Pa2, Pa3, Pw0, Pw1) {                         \
  v8h h0, h1;                                                                \
  h0[0]=(_Float16)Pa0.x; h0[1]=(_Float16)Pa0.y; h0[2]=(_Float16)Pa0.z;       \
  h0[3]=(_Float16)Pa0.w; h0[4]=(_Float16)Pa1.x; h0[5]=(_Float16)Pa1.y;       \
  h0[6]=(_Float16)Pa1.z; h0[7]=(_Float16)Pa1.w;                              \
  h1[0]=(_Float16)Pa2.x; h1[1]=(_Float16)Pa2.y; h1[2]=(_Float16)Pa2.z;       \
  h1[3]=(_Float16)Pa2.w; h1[4]=(_Float16)Pa3.x; h1[5]=(_Float16)Pa3.y;       \
  h1[6]=(_Float16)Pa3.z; h1[7]=(_Float16)Pa3.w;                              \
  *(v8h*)&Asl[buf][sr][sk]     = h0;                                         \
  *(v8h*)&Asl[buf][sr][sk + 8] = h1;                                         \
  *(v8h*)&Wsl[buf][sr][sk]     = Pw0;                                        \
  *(v8h*)&Wsl[buf][sr][sk + 8] = Pw1; }

#define COMPUTET5(buf) {                                                     \
  v8h af[4], bf[4];                                                          \
  _Pragma("unroll")                                                          \
  for (int m = 0; m < 4; ++m)                                                \
    af[m] = *(const v8h*)&Asl[buf][wm * 64 + m * 16 + lr][kk];               \
  _Pragma("unroll")                                                          \
  for (int n = 0; n < 4; ++n)                                                \
    bf[n] = *(const v8h*)&Wsl[buf][wn * 64 + n * 16 + lr][kk];               \
  __builtin_amdgcn_s_setprio(1);                                             \
  _Pragma("unroll")                                                          \
  for (int m = 0; m < 4; ++m)                                                \
    _Pragma("unroll")                                                        \
    for (int n = 0; n < 4; ++n)                                              \
      acc[m][n] = __builtin_amdgcn_mfma_f32_16x16x32_f16(af[m], bf[n],       \
                                                         acc[m][n], 0, 0, 0);\
  __builtin_amdgcn_s_setprio(0); }

#define BARRIER5() {                                                         \
  asm volatile("s_waitcnt lgkmcnt(0)" ::: "memory");                         \
  __builtin_amdgcn_s_barrier(); }

__global__ __launch_bounds__(256, 3) void k_main5(
    const float* __restrict__ A, const _Float16* __restrict__ Wt,
    const float* __restrict__ Wc2s, const float* __restrict__ wscore,
    float* __restrict__ ws) {
  __shared__ _Float16 Asl[2][BM][LDKh];
  __shared__ _Float16 Wsl[2][BN][LDKh];
  const int tid = threadIdx.x;
  const int lane = tid & 63;
  const int wv = tid >> 6;
  const int wm = wv >> 1, wn = wv & 1;
  const int l = blockIdx.x;
  const int lp = (l & 7) * 250 + (l >> 3);
  const int row0 = (lp >> 2) * BM;
  const int c0 = (lp & 3) * BN;
  const int sr = tid >> 1, sk = (tid & 1) * 16;
  const float* __restrict__ asrc = A + (size_t)(row0 + sr) * ENC2n + sk;
  const _Float16* __restrict__ wsrc = Wt + (size_t)(c0 + sr) * ENC2n + sk;
  const int lr = lane & 15, lg = lane >> 4;
  const int kk = lg * 8;

  f32x4 acc[4][4];
#pragma unroll
  for (int m = 0; m < 4; ++m)
#pragma unroll
    for (int n = 0; n < 4; ++n) acc[m][n] = (f32x4)0.f;

  float4 xa0, xa1, xa2, xa3; v8h xw0, xw1;
  float4 ya0, ya1, ya2, ya3; v8h yw0, yw1;

  LOADT5(xa0, xa1, xa2, xa3, xw0, xw1, 0);
  LOADT5(ya0, ya1, ya2, ya3, yw0, yw1, BK);
  STORET5(0, xa0, xa1, xa2, xa3, xw0, xw1);
  BARRIER5();

  for (int t = 0; t < NT - 2; t += 2) {
    LOADT5(xa0, xa1, xa2, xa3, xw0, xw1, (t + 2) * BK);
    COMPUTET5(0);
    STORET5(1, ya0, ya1, ya2, ya3, yw0, yw1);
    BARRIER5();
    LOADT5(ya0, ya1, ya2, ya3, yw0, yw1, (t + 3) * BK);
    COMPUTET5(1);
    STORET5(0, xa0, xa1, xa2, xa3, xw0, xw1);
    BARRIER5();
  }
  COMPUTET5(0);
  STORET5(1, ya0, ya1, ya2, ya3, yw0, yw1);
  BARRIER5();
  COMPUTET5(1);

  __syncthreads();
  float* tcs = (float*)&Asl[0][0][0];
  {
    const float* __restrict__ tsrc = ws + (size_t)row0 * NKn;
    for (int i = tid; i < BM * NKn; i += 256) tcs[i] = tsrc[i];
  }
  __syncthreads();

  const float* __restrict__ DB = ws + OFF_DB;
  float wc2[4][NKn], wsc[4];
  int cl[4];
#pragma unroll
  for (int fn = 0; fn < 4; ++fn) {
    cl[fn] = c0 + wn * 64 + fn * 16 + lr;
    wsc[fn] = wscore[cl[fn]];
#pragma unroll
    for (int k = 0; k < NKn; ++k) wc2[fn][k] = Wc2s[k * ATTNn + cl[fn]];
  }
#pragma unroll
  for (int fm = 0; fm < 4; ++fm) {
#pragma unroll
    for (int r = 0; r < 4; ++r) {
      const int rowL = wm * 64 + fm * 16 + lg * 4 + r;
      const int grow = row0 + rowL;
      const int b = grow / Tn;
      const float* __restrict__ tk = &tcs[rowL * NKn];
      float tkv[NKn];
#pragma unroll
      for (int k = 0; k < NKn; ++k) tkv[k] = tk[k];
      float p = 0.f;
#pragma unroll
      for (int fn = 0; fn < 4; ++fn) {
        float v = acc[fm][fn][r] + DB[b * ATTNn + cl[fn]];
#pragma unroll
        for (int k = 0; k < NKn; ++k) v = fmaf(tkv[k], wc2[fn][k], v);
        p = fmaf(wsc[fn], fast_tanh(v), p);
      }
      p += __shfl_down(p, 8, 16);
      p += __shfl_down(p, 4, 16);
      p += __shfl_down(p, 2, 16);
      p += __shfl_down(p, 1, 16);
      if (lr == 0) atomicAdd(&ws[OFF_SCORE + grow], p);
    }
  }
}

// ---------------------------------------------------------------------------
// k_softmax: masked softmax over T per batch row
// ---------------------------------------------------------------------------
__global__ __launch_bounds__(256) void k_softmax(const float* __restrict__ ws,
                                                 const float* __restrict__ mask,
                                                 float* __restrict__ out) {
  const int b = blockIdx.x, tid = threadIdx.x;
  const float* __restrict__ s = ws + OFF_SCORE + b * Tn;
  const float* __restrict__ mrow = mask + b * Tn;
  float* __restrict__ orow = out + b * Tn;
  __shared__ float red[4];

  float m = -1e30f;
  for (int t = tid; t < Tn; t += 256) m = fmaxf(m, s[t]);
#pragma unroll
  for (int off = 32; off; off >>= 1) m = fmaxf(m, __shfl_down(m, off));
  if ((tid & 63) == 0) red[tid >> 6] = m;
  __syncthreads();
  m = fmaxf(fmaxf(red[0], red[1]), fmaxf(red[2], red[3]));
  __syncthreads();

  float sum = 0.f;
  for (int t = tid; t < Tn; t += 256) {
    const float e = expf(s[t] - m) * mrow[t];
    orow[t] = e;
    sum += e;
  }
#pragma unroll
  for (int off = 32; off; off >>= 1) sum += __shfl_down(sum, off);
  if ((tid & 63) == 0) red[tid >> 6] = sum;
  __syncthreads();
  sum = red[0] + red[1] + red[2] + red[3];
  const float inv = 1.f / sum;
  for (int t = tid; t < Tn; t += 256) orow[t] *= inv;
}

// ---------------------------------------------------------------------------
extern "C" void kernel_launch(void* const* d_in, const int* in_sizes, int n_in,
                              void* d_out, int out_size, void* d_ws, size_t ws_size,
                              hipStream_t stream) {
  const float* enc   = (const float*)d_in[0];
  const float* hid   = (const float*)d_in[1];
  const float* alpha = (const float*)d_in[2];
  const float* mask  = (const float*)d_in[3];
  const float* Wconv = (const float*)d_in[4];
  const float* Wc2s  = (const float*)d_in[5];
  const float* Wenc  = (const float*)d_in[6];
  const float* benc  = (const float*)d_in[7];
  const float* Wdec  = (const float*)d_in[8];
  const float* wscr  = (const float*)d_in[9];
  float* out = (float*)d_out;
  float* ws  = (float*)d_ws;
  _Float16* Wt = (_Float16*)(ws + OFF_WT);
  _Float16* Af = (_Float16*)(ws + OFF_AF16);

  k_wt<<<dim3(ENC2n / 32, ATTNn / 32), 256, 0, stream>>>(Wenc, Wt);
  k_conv<<<dim3((Tn + 255) / 256, Bn), 256, 0, stream>>>(alpha, Wconv, ws);
  k_dec<<<Bn, DECn, 0, stream>>>(hid, Wdec, benc, ws);
  if (ws_size >= WS_NEED_BYTES) {
    k_acvt<<<4096, 256, 0, stream>>>(enc, Af);
    k_main<<<2000, 256, 0, stream>>>(Af, Wt, Wc2s, wscr, ws);
  } else {
    k_main5<<<2000, 256, 0, stream>>>(enc, Wt, Wc2s, wscr, ws);
  }
  k_softmax<<<Bn, 256, 0, stream>>>(ws, mask, out);
}